// Round 4
// baseline (2366.928 us; speedup 1.0000x reference)
//
#include <hip/hip_runtime.h>

typedef unsigned short u16;
typedef __bf16 bf16x8 __attribute__((ext_vector_type(8)));
typedef float f32x4 __attribute__((ext_vector_type(4)));

#define MFMA16(a,b,c) __builtin_amdgcn_mfma_f32_16x16x32_bf16(a,b,c,0,0,0)

// B=2048 S=64 E=256 D=512 IN=32 T=64 ; step-GEMM K = 32+512 = 544
#define NB 2048
#define NS 64
#define NE 256
#define ND 512
#define NT 64
#define UW 288
// MFMA-tile format (TF): operand[rowtile][ktile][lane][8], tile = 512 u16 = 1KB.
// Slab: 128 rowtiles x 17 ktiles. elem(b,k) -> ((b>>4)*17 + (k>>5))*512 + (((k&31)>>3)*16 + (b&15))*8 + (k&7)
#define SLABTF (128*17*512)

__device__ __forceinline__ void ld16(void* lds, const void* g) {
  __builtin_amdgcn_global_load_lds(
      (__attribute__((address_space(1))) void*)(uintptr_t)g,
      (__attribute__((address_space(3))) void*)(unsigned int)(uintptr_t)lds,
      16, 0, 0);
}
__device__ __forceinline__ u16 f2bf(float f) {
  union { float f; unsigned u; } v; v.f = f;
  unsigned r = v.u + 0x7FFFu + ((v.u >> 16) & 1u);
  return (u16)(r >> 16);
}
__device__ __forceinline__ float bf2f(u16 h) {
  union { unsigned u; float f; } v; v.u = ((unsigned)h) << 16;
  return v.f;
}
__device__ __forceinline__ float sig(float x) { return 1.f / (1.f + __expf(-x)); }
__device__ __forceinline__ float tanh_(float x) {
  float ax = fabsf(x);
  float e = __expf(-2.f * ax);
  float r = (1.f - e) / (1.f + e);
  return copysignf(r, x);
}

// ---------------- phase A ----------------

__global__ __launch_bounds__(256) void prep_enc(
    const float* __restrict__ cEnc, const float* __restrict__ Wfc,
    const float* __restrict__ hist, const float* __restrict__ cur,
    float* __restrict__ inp0, float* __restrict__ cw, u16* __restrict__ cEncB)
{
  __shared__ float meanP[4][256];
  int tid = threadIdx.x, lane = tid & 63, w = tid >> 6;
  int b = blockIdx.x;
  const float* base = cEnc + (size_t)b * NS * NE;
  float4 wf = *(const float4*)(Wfc + lane * 4);
  float m0 = 0, m1 = 0, m2 = 0, m3 = 0;
  for (int s = w * 16; s < w * 16 + 16; ++s) {
    float4 v = *(const float4*)(base + s * NE + lane * 4);
    m0 += v.x; m1 += v.y; m2 += v.z; m3 += v.w;
    ushort4 bv;
    bv.x = f2bf(v.x); bv.y = f2bf(v.y); bv.z = f2bf(v.z); bv.w = f2bf(v.w);
    *(ushort4*)(cEncB + (size_t)b * NS * NE + s * NE + lane * 4) = bv;
    float d = v.x * wf.x + v.y * wf.y + v.z * wf.z + v.w * wf.w;
    for (int off = 32; off; off >>= 1) d += __shfl_xor(d, off);
    if (lane == 0) cw[b * NS + s] = d;
  }
  meanP[w][lane*4+0] = m0; meanP[w][lane*4+1] = m1;
  meanP[w][lane*4+2] = m2; meanP[w][lane*4+3] = m3;
  __syncthreads();
  {
    float s = meanP[0][tid] + meanP[1][tid] + meanP[2][tid] + meanP[3][tid];
    inp0[(size_t)b * 288 + tid] = s * (1.f / 64.f);
  }
  if (tid < 32) {
    float x = (tid < 31) ? hist[b * 31 + tid] : cur[b * NT + 0];
    inp0[(size_t)b * 288 + 256 + tid] = x;
  }
}

// speed cols (kt=0) of slabs 0..63, TF layout
__global__ void xfill(const float* __restrict__ hist, const float* __restrict__ cur,
                      u16* __restrict__ XT)
{
  int idx = blockIdx.x * 256 + threadIdx.x;   // 64*2048*32
  int k = idx & 31, b = (idx >> 5) & 2047, t = idx >> 16;
  int j = t + k - 31;
  float x = (j >= 0) ? cur[b * NT + j] : hist[b * 31 + t + k];
  XT[(size_t)t * SLABTF + ((size_t)(b >> 4) * 17) * 512 +
     (((k >> 3) * 16) + (b & 15)) * 8 + (k & 7)] = f2bf(x);
}

// LSTM weights, TF: 128 coltiles (cg = dg*4 + gate, col cn -> d = dg*16+cn) x 17 kt
__global__ void cast_wc4(const float* __restrict__ Wih, const float* __restrict__ Whh,
                         u16* __restrict__ O)
{
  int gid = blockIdx.x * 256 + threadIdx.x;   // 2048*544
  if (gid >= 2048 * 544) return;
  int tile = gid >> 9, within = gid & 511;
  int l = within >> 3, e = within & 7;
  int kt = tile % 17, cg = tile / 17;
  int gate = cg & 3, dg = cg >> 2;
  int cn = l & 15, q = l >> 4;
  int d = dg * 16 + cn;
  int j = gate * 512 + d;
  int k = kt * 32 + q * 8 + e;
  float v = (k < 32) ? Wih[j * 32 + k] : Whh[j * 512 + (k - 32)];
  O[gid] = f2bf(v);
}

__global__ void bsum_k(const float* __restrict__ bih, const float* __restrict__ bhh,
                       float* __restrict__ bsum)
{
  int i = blockIdx.x * 256 + threadIdx.x;
  if (i < 2048) bsum[i] = bih[i] + bhh[i];
}

// Wproj TF: 56 coltiles x 16 kt. col c = ctile*16+cn: c<512 -> Wwp; 512+n: n<256 Wwa, 256 bwa, 257 WfcD
__global__ void cast_wproj(const float* __restrict__ Wwp, const float* __restrict__ Wwa,
                           const float* __restrict__ bwa, const float* __restrict__ Wfc,
                           u16* __restrict__ O)
{
  int gid = blockIdx.x * 256 + threadIdx.x;   // 56*16*512
  if (gid >= 56 * 16 * 512) return;
  int tile = gid >> 9, within = gid & 511;
  int l = within >> 3, e = within & 7;
  int kt = tile & 15, ctile = tile >> 4;
  int c = ctile * 16 + (l & 15);
  int k = kt * 32 + (l >> 4) * 8 + e;
  float v = 0.f;
  if (c < 512) v = Wwp[c * 512 + k];
  else {
    int n = c - 512;
    if (n < 256) v = Wwa[k * 256 + n];
    else if (n == 256) v = bwa[k];
    else if (n == 257) v = Wfc[256 + k];
  }
  O[gid] = f2bf(v);
}

// h0/c0; h0 -> slab0 TF (kt 1..16), c0 -> cbuf fp32
__global__ __launch_bounds__(256) void init_gemm(
    const float* __restrict__ inp0, const float* __restrict__ Wh, const float* __restrict__ Wc,
    const float* __restrict__ bh, const float* __restrict__ bc,
    u16* __restrict__ XT0, float* __restrict__ cbuf)
{
  __shared__ float As[64][33];
  __shared__ float Bs[64][33];
  int tid = threadIdx.x;
  int b0 = blockIdx.x * 64, n0 = blockIdx.y * 64;
  int tx = tid & 15, ty = tid >> 4;
  float acc[4][4] = {};
  for (int kk = 0; kk < 9; ++kk) {
    for (int sw = 0; sw < 2; ++sw) {
      int idx = sw * 256 + tid;
      int row = idx >> 3, c4 = idx & 7;
      float4 av = *(const float4*)(inp0 + (size_t)(b0 + row) * 288 + kk * 32 + c4 * 4);
      As[row][c4*4+0] = av.x; As[row][c4*4+1] = av.y; As[row][c4*4+2] = av.z; As[row][c4*4+3] = av.w;
      int n = n0 + row;
      const float* bs = (n < 512) ? (Wh + (size_t)n * 288) : (Wc + (size_t)(n - 512) * 288);
      float4 bv = *(const float4*)(bs + kk * 32 + c4 * 4);
      Bs[row][c4*4+0] = bv.x; Bs[row][c4*4+1] = bv.y; Bs[row][c4*4+2] = bv.z; Bs[row][c4*4+3] = bv.w;
    }
    __syncthreads();
    for (int k = 0; k < 32; ++k) {
      float a4[4], b4[4];
      #pragma unroll
      for (int i = 0; i < 4; ++i) a4[i] = As[ty * 4 + i][k];
      #pragma unroll
      for (int j = 0; j < 4; ++j) b4[j] = Bs[tx * 4 + j][k];
      #pragma unroll
      for (int i = 0; i < 4; ++i)
        #pragma unroll
        for (int j = 0; j < 4; ++j) acc[i][j] += a4[i] * b4[j];
    }
    __syncthreads();
  }
  for (int i = 0; i < 4; ++i)
    for (int j = 0; j < 4; ++j) {
      int b = b0 + ty * 4 + i, n = n0 + tx * 4 + j;
      float v = acc[i][j];
      if (n < 512) {
        int kt = 1 + (n >> 5);
        XT0[((size_t)(b >> 4) * 17 + kt) * 512 +
            ((((n & 31) >> 3) * 16) + (b & 15)) * 8 + (n & 7)] = f2bf(v + bh[n]);
      } else cbuf[(size_t)b * ND + n - 512] = v + bc[n - 512];
    }
}

// ---------------- phase B: persistent LSTM ----------------
// grid 256 (= 8 rb x 32 dg), 1 block/CU (LDS-padded). Weights resident in LDS
// (kt 0..14) + regs (kt 15,16); c-state in regs; barrier-free K-loop;
// device-scope grid barrier between steps.
__device__ __forceinline__ void gridbar(unsigned* bar, unsigned target) {
  __syncthreads();
  if (threadIdx.x == 0) {
    __threadfence();
    __hip_atomic_fetch_add(bar, 1u, __ATOMIC_RELEASE, __HIP_MEMORY_SCOPE_AGENT);
    while (__hip_atomic_load(bar, __ATOMIC_ACQUIRE, __HIP_MEMORY_SCOPE_AGENT) < target) {
      __builtin_amdgcn_s_sleep(2);
    }
    __threadfence();
  }
  __syncthreads();
}

__global__ __launch_bounds__(256, 1) void lstm_persist(
    u16* __restrict__ XT, const u16* __restrict__ Wc4,
    const float* __restrict__ bsum, const float* __restrict__ cbuf,
    unsigned* __restrict__ bar)
{
  __shared__ u16 Bw[4 * 15 * 512];       // 61440 B; + dynamic pad -> 1 block/CU
  extern __shared__ char occupancy_pad[];
  (void)occupancy_pad;
  int tid = threadIdx.x, lane = tid & 63, w = tid >> 6;
  int col = lane & 15, quad = lane >> 4;
  int rb = blockIdx.x & 7, dg = blockIdx.x >> 3;   // same rb -> same XCD (L2 reuse of A)
  const u16* wsrc = Wc4 + (size_t)(dg * 4) * 17 * 512;
  for (int i = tid; i < 3840; i += 256) {
    int ct = i / 960, r2 = i % 960, kt = r2 >> 6, cc = r2 & 63;
    ld16(&Bw[((ct * 15 + kt) * 512 + cc * 8)],
         wsrc + ((size_t)(ct * 17 + kt) * 512 + cc * 8));
  }
  bf16x8 bp[2][4];
  #pragma unroll
  for (int kt = 0; kt < 2; ++kt)
    #pragma unroll
    for (int nt = 0; nt < 4; ++nt)
      bp[kt][nt] = *(const bf16x8*)(wsrc + ((size_t)(nt * 17 + 15 + kt) * 512 + lane * 8));
  int d = dg * 16 + col;
  float cst[4][4];
  #pragma unroll
  for (int mt = 0; mt < 4; ++mt)
    #pragma unroll
    for (int r = 0; r < 4; ++r) {
      int row = rb * 256 + w * 64 + mt * 16 + quad * 4 + r;
      cst[mt][r] = cbuf[(size_t)row * ND + d];
    }
  float bi = bsum[d], bf_ = bsum[512 + d], bg = bsum[1024 + d], bo = bsum[1536 + d];
  __syncthreads();
  int rt0 = rb * 16 + w * 4;
  int kt_o = (dg + 2) >> 1, khi = dg & 1;
  #pragma unroll 1
  for (int t = 0; t < 64; ++t) {
    const u16* slab = XT + (size_t)t * SLABTF;
    u16* nslab = XT + (size_t)(t + 1) * SLABTF;
    f32x4 acc[4][4] = {};
    bf16x8 a0[4], a1[4];
    #pragma unroll
    for (int mt = 0; mt < 4; ++mt)
      a0[mt] = *(const bf16x8*)(slab + ((size_t)(rt0 + mt) * 17) * 512 + lane * 8);
    #pragma unroll
    for (int kk = 0; kk < 17; ++kk) {
      bf16x8* ac = (kk & 1) ? a1 : a0;
      bf16x8* an = (kk & 1) ? a0 : a1;
      if (kk < 16) {
        #pragma unroll
        for (int mt = 0; mt < 4; ++mt)
          an[mt] = *(const bf16x8*)(slab + ((size_t)(rt0 + mt) * 17 + kk + 1) * 512 + lane * 8);
      }
      #pragma unroll
      for (int nt = 0; nt < 4; ++nt) {
        bf16x8 bb = (kk < 15) ? *(const bf16x8*)&Bw[((nt * 15 + kk) * 512 + lane * 8)]
                              : bp[kk - 15][nt];
        #pragma unroll
        for (int mt = 0; mt < 4; ++mt) acc[mt][nt] = MFMA16(ac[mt], bb, acc[mt][nt]);
      }
    }
    #pragma unroll
    for (int mt = 0; mt < 4; ++mt) {
      int rt = rt0 + mt;
      #pragma unroll
      for (int r = 0; r < 4; ++r) {
        float gi = acc[mt][0][r] + bi;
        float gf = acc[mt][1][r] + bf_;
        float gg = acc[mt][2][r] + bg;
        float go = acc[mt][3][r] + bo;
        float c2 = sig(gf) * cst[mt][r] + sig(gi) * tanh_(gg);
        cst[mt][r] = c2;
        float h2 = sig(go) * tanh_(c2);
        int slot = (khi * 2 + (col >> 3)) * 16 + quad * 4 + r;
        nslab[((size_t)rt * 17 + kt_o) * 512 + slot * 8 + (col & 7)] = f2bf(h2);
      }
    }
    if (t < 63) gridbar(bar, 256u * (t + 1));
  }
}

// ---------------- phase C: projection GEMM, ct-loop inside ----------------
__global__ __launch_bounds__(256) void proj_gemm(
    const u16* __restrict__ XT, const u16* __restrict__ Wp,
    const float* __restrict__ bwp, const float* __restrict__ vp,
    float* __restrict__ apart, u16* __restrict__ UT)
{
  __shared__ __align__(16) u16 As[3][4096];
  __shared__ __align__(16) u16 Bs[3][4096];
  int tid = threadIdx.x, lane = tid & 63, w = tid >> 6;
  int col = lane & 15, quad = lane >> 4;
  int bx = blockIdx.x;
  int t = bx >> 4, rb = bx & 15;
  const u16* slab = XT + (size_t)(t + 1) * SLABTF;
  size_t r0 = (size_t)bx * 128;
  auto stageA = [&](u16* dst, int kk) {
    #pragma unroll
    for (int sw = 0; sw < 2; ++sw) {
      int s = sw * 256 + tid;
      ld16(dst + s * 8, slab + ((size_t)(rb * 8 + (s >> 6)) * 17 + kk + 1) * 512 + (s & 63) * 8);
    }
  };
  auto stageB = [&](u16* dst, int ct, int kk) {
    #pragma unroll
    for (int sw = 0; sw < 2; ++sw) {
      int s = sw * 256 + tid;
      ld16(dst + s * 8, Wp + ((size_t)(ct * 8 + (s >> 6)) * 16 + kk) * 512 + (s & 63) * 8);
    }
  };
  stageA(As[0], 0); stageB(Bs[0], 0, 0);
  stageA(As[1], 1); stageB(Bs[1], 0, 1);
  f32x4 acc[4][4] = {};
  for (int j = 0; j < 112; ++j) {
    int ct = j >> 4, kk = j & 15;
    __syncthreads();
    if (j + 2 < 112) {
      int m = (j + 2) % 3;
      stageA(As[m], (j + 2) & 15);
      stageB(Bs[m], (j + 2) >> 4, (j + 2) & 15);
    }
    {
      const u16* A = As[j % 3];
      const u16* Bt = Bs[j % 3];
      bf16x8 a[4], b[4];
      #pragma unroll
      for (int mt = 0; mt < 4; ++mt)
        a[mt] = *(const bf16x8*)&A[(((w >> 1) * 4 + mt) * 512 + lane * 8)];
      #pragma unroll
      for (int nt = 0; nt < 4; ++nt)
        b[nt] = *(const bf16x8*)&Bt[(((w & 1) * 4 + nt) * 512 + lane * 8)];
      #pragma unroll
      for (int mt = 0; mt < 4; ++mt)
        #pragma unroll
        for (int nt = 0; nt < 4; ++nt) acc[mt][nt] = MFMA16(a[mt], b[nt], acc[mt][nt]);
    }
    if (kk == 15) {
      if (ct < 4) {
        float part[4][4] = {};
        #pragma unroll
        for (int nt = 0; nt < 4; ++nt) {
          int oc = ct * 128 + (w & 1) * 64 + nt * 16 + col;
          float bw = bwp[oc], vv = vp[oc];
          #pragma unroll
          for (int mt = 0; mt < 4; ++mt)
            #pragma unroll
            for (int r = 0; r < 4; ++r) part[mt][r] += tanh_(acc[mt][nt][r] + bw) * vv;
        }
        #pragma unroll
        for (int mt = 0; mt < 4; ++mt)
          #pragma unroll
          for (int r = 0; r < 4; ++r) {
            float p = part[mt][r];
            p += __shfl_xor(p, 1); p += __shfl_xor(p, 2);
            p += __shfl_xor(p, 4); p += __shfl_xor(p, 8);
            if (col == 0)
              atomicAdd(&apart[r0 + (w >> 1) * 64 + mt * 16 + quad * 4 + r], p);
          }
      } else {
        #pragma unroll
        for (int nt = 0; nt < 4; ++nt) {
          int uc = (ct - 4) * 128 + (w & 1) * 64 + nt * 16 + col;
          if (uc < UW) {
            #pragma unroll
            for (int mt = 0; mt < 4; ++mt)
              #pragma unroll
              for (int r = 0; r < 4; ++r) {
                size_t row = r0 + (w >> 1) * 64 + mt * 16 + quad * 4 + r;
                int tt = (int)(row >> 11), b = (int)(row & 2047);
                UT[((size_t)b * NT + tt) * UW + uc] = f2bf(acc[mt][nt][r]);
              }
          }
        }
      }
      #pragma unroll
      for (int mt = 0; mt < 4; ++mt)
        #pragma unroll
        for (int nt = 0; nt < 4; ++nt) acc[mt][nt] = f32x4{0.f, 0.f, 0.f, 0.f};
    }
  }
}

__global__ void finish_aligned(const float* __restrict__ apart,
                               const float* __restrict__ bvp,
                               float* __restrict__ alg)
{
  int i = blockIdx.x * 256 + threadIdx.x;
  if (i < 131072) alg[i] = 64.f * sig(apart[i] + bvp[0]);
}

// ---------------- attention ----------------
__global__ __launch_bounds__(256) void attn_kernel(
    const u16* __restrict__ cEncB, const u16* __restrict__ UT,
    const float* __restrict__ alignedIn, const float* __restrict__ cw,
    const float* __restrict__ bfc,
    float* __restrict__ preds, float* __restrict__ alphas)
{
  __shared__ __align__(16) u16 Ae[64 * 256];
  __shared__ __align__(16) u16 Ue[64 * 256];
  __shared__ float attL[64 * 68];
  __shared__ float s0L[64], hwL[64], alL[64], cwL[64], mL[64], zL[64];
  __shared__ float red[4][64];
  int tid = threadIdx.x, lane = tid & 63, w = tid >> 6;
  int col = lane & 15, quad = lane >> 4;
  int b = blockIdx.x;
  const u16* eb = cEncB + (size_t)b * NS * NE;
  const u16* ub = UT + (size_t)b * NT * UW;
  for (int sw = 0; sw < 8; ++sw) {
    int idx = sw * 256 + tid;
    int r = idx >> 5, cs = idx & 31, g = cs ^ (r & 7);
    ld16(&Ae[idx * 8], eb + (size_t)r * NE + g * 8);
    ld16(&Ue[idx * 8], ub + (size_t)r * UW + g * 8);
  }
  if (tid < 64) {
    s0L[tid] = bf2f(ub[tid * UW + 256]);
    hwL[tid] = bf2f(ub[tid * UW + 257]);
    alL[tid] = alignedIn[(size_t)tid * NB + b];
    cwL[tid] = cw[b * NS + tid];
  }
  __syncthreads();
  f32x4 acc[4] = {};
  int rowA = w * 16 + col;
  #pragma unroll
  for (int kk = 0; kk < 8; ++kk) {
    int ga = (kk * 4 + quad);
    bf16x8 a = *(const bf16x8*)&Ae[(rowA * 32 + (ga ^ (rowA & 7))) * 8];
    #pragma unroll
    for (int nt = 0; nt < 4; ++nt) {
      int rowB = nt * 16 + col;
      bf16x8 bb = *(const bf16x8*)&Ue[(rowB * 32 + (ga ^ (rowB & 7))) * 8];
      acc[nt] = MFMA16(a, bb, acc[nt]);
    }
  }
  for (int nt = 0; nt < 4; ++nt) {
    int t = nt * 16 + col;
    #pragma unroll
    for (int r = 0; r < 4; ++r) {
      int s = w * 16 + quad * 4 + r;
      attL[s * 68 + t] = acc[nt][r] + s0L[t];
    }
  }
  __syncthreads();
  int t = tid & 63, qq = tid >> 6;
  float pm = -1e30f;
  for (int s = qq * 16; s < qq * 16 + 16; ++s) pm = fmaxf(pm, attL[s * 68 + t]);
  red[qq][t] = pm;
  __syncthreads();
  if (tid < 64)
    mL[tid] = fmaxf(fmaxf(red[0][tid], red[1][tid]), fmaxf(red[2][tid], red[3][tid]));
  __syncthreads();
  float m = mL[t];
  float ps = 0.f;
  for (int s = qq * 16; s < qq * 16 + 16; ++s) ps += __expf(attL[s * 68 + t] - m);
  red[qq][t] = ps;
  __syncthreads();
  if (tid < 64) zL[tid] = red[0][tid] + red[1][tid] + red[2][tid] + red[3][tid];
  __syncthreads();
  float zinv = 1.f / zL[t];
  float al = alL[t];
  float pp = 0.f;
  float* aout = alphas + (size_t)b * (NT * NS) + t * NS;
  for (int s = qq * 16; s < qq * 16 + 16; ++s) {
    float e = __expf(attL[s * 68 + t] - m) * zinv;
    float ds = (float)s - al;
    float a = e * __expf(-0.5f * ds * ds);
    aout[s] = a;
    pp += a * cwL[s];
  }
  red[qq][t] = pp;
  __syncthreads();
  if (tid < 64)
    preds[(size_t)b * NT + tid] =
        red[0][tid] + red[1][tid] + red[2][tid] + red[3][tid] + hwL[tid] + bfc[0];
}

extern "C" void kernel_launch(void* const* d_in, const int* in_sizes, int n_in,
                              void* d_out, int out_size, void* d_ws, size_t ws_size,
                              hipStream_t stream) {
  const float* cEnc = (const float*)d_in[0];
  const float* cur  = (const float*)d_in[1];
  const float* hist = (const float*)d_in[2];
  const float* WIh  = (const float*)d_in[6];
  const float* bIh  = (const float*)d_in[7];
  const float* WIc  = (const float*)d_in[8];
  const float* bIc  = (const float*)d_in[9];
  const float* Wih  = (const float*)d_in[10];
  const float* Whh  = (const float*)d_in[11];
  const float* bih  = (const float*)d_in[12];
  const float* bhh  = (const float*)d_in[13];
  const float* Wwa  = (const float*)d_in[14];
  const float* bwa  = (const float*)d_in[15];
  const float* Wwp  = (const float*)d_in[16];
  const float* bwp  = (const float*)d_in[17];
  const float* Wvp  = (const float*)d_in[18];
  const float* bvp  = (const float*)d_in[19];
  const float* Wfc  = (const float*)d_in[20];
  const float* bfc  = (const float*)d_in[21];
  float* preds  = (float*)d_out;
  float* alphas = preds + (size_t)NB * NT;

  char* ws = (char*)d_ws;
  size_t off = 0;
  auto alloc = [&](size_t bytes) { void* p = ws + off; off += (bytes + 255) & ~(size_t)255; return p; };
  u16*   XT    = (u16*)  alloc((size_t)65 * SLABTF * 2);
  u16*   UT    = (u16*)  alloc((size_t)NB * NT * UW * 2);
  u16*   cEncB = (u16*)  alloc((size_t)NB * NS * NE * 2);
  float* cbuf  = (float*)alloc((size_t)NB * ND * 4);
  float* inp0  = (float*)alloc((size_t)NB * 288 * 4);
  float* cwb   = (float*)alloc((size_t)NB * NS * 4);
  float* alg   = (float*)alloc((size_t)131072 * 4);
  float* apart = (float*)alloc((size_t)131072 * 4);
  u16*   Wc4   = (u16*)  alloc((size_t)2048 * 544 * 2);
  u16*   WpTF  = (u16*)  alloc((size_t)56 * 16 * 512 * 2);
  float* bsum  = (float*)alloc((size_t)2048 * 4);
  unsigned* bar = (unsigned*)alloc(256);

  prep_enc<<<NB, 256, 0, stream>>>(cEnc, Wfc, hist, cur, inp0, cwb, cEncB);
  xfill<<<16384, 256, 0, stream>>>(hist, cur, XT);
  cast_wc4<<<4352, 256, 0, stream>>>(Wih, Whh, Wc4);
  bsum_k<<<8, 256, 0, stream>>>(bih, bhh, bsum);
  cast_wproj<<<1792, 256, 0, stream>>>(Wwp, Wwa, bwa, Wfc, WpTF);
  init_gemm<<<dim3(32, 16), 256, 0, stream>>>(inp0, WIh, WIc, bIh, bIc, XT, cbuf);
  hipMemsetAsync(apart, 0, (size_t)131072 * 4, stream);
  hipMemsetAsync(bar, 0, 256, stream);
  // dynamic LDS pad (20480 B) => 61440+20480 = 80 KiB+ per block => 1 block/CU
  lstm_persist<<<256, 256, 20480, stream>>>(XT, Wc4, bsum, cbuf, bar);
  proj_gemm<<<1024, 256, 0, stream>>>(XT, WpTF, bwp, Wvp, apart, UT);
  finish_aligned<<<512, 256, 0, stream>>>(apart, bvp, alg);
  attn_kernel<<<NB, 256, 0, stream>>>(cEncB, UT, alg, cwb, bfc, preds, alphas);
}